// Round 5
// baseline (374.491 us; speedup 1.0000x reference)
//
#include <hip/hip_runtime.h>

// EMA y_t = w*x_t + (1-w)*y_{t-1}, a = 1-w per-channel constant.
// Single fused kernel, chunked scan with decoupled lookback.
//
// R3 lesson: agent-scope acquire/release -> buffer_inv/wbl2 storms. Use only
// relaxed agent atomics (sc0 sc1: straight to L3, the coherence point).
// R4 lesson: unthrottled 64-lane polling of 8KB of flags hammers a few L3
// banks and serializes the chip. Fixes: flags padded to 1 line each, 8 polling
// lanes per wave, s_sleep backoff, batch-8 lookback with normal vector loads.
//
// grid = B*P blocks (P=T/64), 1 wave per block, 4 channels/lane.
// __launch_bounds__(64,4) caps VGPR at 128 -> >=4096 single-wave blocks
// co-resident >= 2048 launched: spin-wait cannot deadlock.

#define CHUNK_L 64
#define FLAG_STRIDE 16  // dwords; one 64B line per flag

__device__ __forceinline__ float clip01(float v) {
    return fminf(fmaxf(v, 0.0f), 1.0f);
}

__global__ __launch_bounds__(64, 4) void ema_fused(
    const float* __restrict__ x, const float* __restrict__ smooth,
    const float* __restrict__ init, float* __restrict__ out,
    float* __restrict__ chunk_last, unsigned int* __restrict__ flags,
    int T, int C, int P) {
    const int blk = blockIdx.x;          // b*P + p
    const int b = blk / P;
    const int p = blk - b * P;
    const int lane = threadIdx.x;
    const int c = lane << 2;             // 4 channels per lane

    float4 w4 = *(const float4*)(smooth + c);
    w4.x = clip01(w4.x); w4.y = clip01(w4.y); w4.z = clip01(w4.z); w4.w = clip01(w4.w);
    const float ax = 1.0f - w4.x, ay = 1.0f - w4.y, az = 1.0f - w4.z, aw = 1.0f - w4.w;

    // aL = a^CHUNK_L by repeated squaring
    float aLx = ax, aLy = ay, aLz = az, aLw = aw;
    for (int e = CHUNK_L; e > 1; e >>= 1) { aLx *= aLx; aLy *= aLy; aLz *= aLz; aLw *= aLw; }

    const int sF4 = C >> 2;
    const size_t base = ((size_t)b * T + (size_t)p * CHUNK_L) * C;
    const float4* xp = (const float4*)(x + base) + lane;
    float4* op = (float4*)(out + base) + lane;

    // ---- Phase 1: local scan, zero seed ----
    float y0 = 0.0f, y1 = 0.0f, y2 = 0.0f, y3 = 0.0f;
    for (int i0 = 0; i0 < CHUNK_L; i0 += 8) {
        float4 xv[8];
#pragma unroll
        for (int j = 0; j < 8; ++j) xv[j] = xp[(size_t)(i0 + j) * sF4];
#pragma unroll
        for (int j = 0; j < 8; ++j) {
            y0 = fmaf(ax, y0, w4.x * xv[j].x);
            y1 = fmaf(ay, y1, w4.y * xv[j].y);
            y2 = fmaf(az, y2, w4.z * xv[j].z);
            y3 = fmaf(aw, y3, w4.w * xv[j].w);
        }
    }

    // ---- Phase 2: publish aggregate (relaxed agent atomics -> L3) ----
    if (p < P - 1) {
        float* dst = chunk_last + (size_t)blk * C + c;
        __hip_atomic_store(dst + 0, y0, __ATOMIC_RELAXED, __HIP_MEMORY_SCOPE_AGENT);
        __hip_atomic_store(dst + 1, y1, __ATOMIC_RELAXED, __HIP_MEMORY_SCOPE_AGENT);
        __hip_atomic_store(dst + 2, y2, __ATOMIC_RELAXED, __HIP_MEMORY_SCOPE_AGENT);
        __hip_atomic_store(dst + 3, y3, __ATOMIC_RELAXED, __HIP_MEMORY_SCOPE_AGENT);
        __atomic_signal_fence(__ATOMIC_SEQ_CST);
        __builtin_amdgcn_s_waitcnt(0);               // drain this wave's stores to L3
        __atomic_signal_fence(__ATOMIC_SEQ_CST);
        if (lane == 0)
            __hip_atomic_store(&flags[(size_t)blk * FLAG_STRIDE], 1u,
                               __ATOMIC_RELAXED, __HIP_MEMORY_SCOPE_AGENT);
    }

    // ---- Phase 3: lookback, batch-8, sleep-backoff polling ----
    float sx = 0.0f, sy = 0.0f, sz = 0.0f, sw = 0.0f;  // sum of f * last_q
    float fx = 1.0f, fy = 1.0f, fz = 1.0f, fw = 1.0f;  // f = aL^(p-1-q)
    const float* cl = chunk_last + ((size_t)b * P) * C + c;
    const unsigned int* fl = flags + (size_t)b * P * FLAG_STRIDE;
    int q = p - 1;
    while (q >= 0) {
        const int nb = (q >= 7) ? 8 : (q + 1);
        // lanes 0..nb-1 poll distinct flags; others poll flag[q] (harmless)
        const unsigned int* myf = fl + (size_t)(q - ((lane < nb) ? lane : 0)) * FLAG_STRIDE;
        while (true) {
            unsigned int f = __hip_atomic_load(myf, __ATOMIC_RELAXED, __HIP_MEMORY_SCOPE_AGENT);
            if (__all(f == 1u)) break;
            __builtin_amdgcn_s_sleep(2);             // ~128 cyc backoff
        }
        __atomic_signal_fence(__ATOMIC_ACQUIRE);     // no compiler hoist of data loads
        float4 l[8];
        for (int j = 0; j < nb; ++j) l[j] = *(const float4*)(cl + (size_t)(q - j) * C);
        for (int j = 0; j < nb; ++j) {
            sx = fmaf(fx, l[j].x, sx); fx *= aLx;
            sy = fmaf(fy, l[j].y, sy); fy *= aLy;
            sz = fmaf(fz, l[j].z, sz); fz *= aLz;
            sw = fmaf(fw, l[j].w, sw); fw *= aLw;
        }
        q -= nb;
    }
    // carry-in = sum + aL^p * init
    const float4 s4 = *(const float4*)(init + (size_t)b * C + c);
    y0 = fmaf(fx, s4.x, sx);
    y1 = fmaf(fy, s4.y, sy);
    y2 = fmaf(fz, s4.z, sz);
    y3 = fmaf(fw, s4.w, sw);

    // ---- Phase 4: apply — re-stream chunk (L3-warm), write out ----
    for (int i0 = 0; i0 < CHUNK_L; i0 += 8) {
        float4 xv[8];
#pragma unroll
        for (int j = 0; j < 8; ++j) xv[j] = xp[(size_t)(i0 + j) * sF4];
#pragma unroll
        for (int j = 0; j < 8; ++j) {
            y0 = fmaf(ax, y0, w4.x * xv[j].x);
            y1 = fmaf(ay, y1, w4.y * xv[j].y);
            y2 = fmaf(az, y2, w4.z * xv[j].z);
            y3 = fmaf(aw, y3, w4.w * xv[j].w);
            float4 r; r.x = y0; r.y = y1; r.z = y2; r.w = y3;
            op[(size_t)(i0 + j) * sF4] = r;
        }
    }
}

extern "C" void kernel_launch(void* const* d_in, const int* in_sizes, int n_in,
                              void* d_out, int out_size, void* d_ws, size_t ws_size,
                              hipStream_t stream) {
    const float* x      = (const float*)d_in[0];  // [B, T, C]
    const float* init   = (const float*)d_in[1];  // [B, C]
    const float* smooth = (const float*)d_in[2];  // [C]
    float* out = (float*)d_out;

    const int C  = in_sizes[2];
    const int BC = in_sizes[1];
    const int B  = BC / C;
    const int T  = in_sizes[0] / BC;
    const int P  = T / CHUNK_L;

    float* chunk_last   = (float*)d_ws;                                     // [B, P, C]
    unsigned int* flags = (unsigned int*)(chunk_last + (size_t)B * P * C);  // [B*P*16]

    ema_fused<<<dim3(B * P), dim3(C / 4), 0, stream>>>(
        x, smooth, init, out, chunk_last, flags, T, C, P);
}